// Round 1
// baseline (41.018 us; speedup 1.0000x reference)
//
#include <hip/hip_runtime.h>
#include <math.h>

// Problem constants (fixed by setup_inputs): B=2, K=128, L=4096, DK=DL=128, HID=128
constexpr int BB = 2;
constexpr int KK = 128;
constexpr int LL = 4096;
constexpr int DD = 128;   // DK == DL
constexpr int HH = 128;   // HID

__device__ __forceinline__ float4 ld4(const float* p) {
    return *reinterpret_cast<const float4*>(p);
}

// ---------------------------------------------------------------------------
// k1: compute u[b,k,h] = (inputA @ W1[:128])[b,k,h] + b1[h]   (rows 0..255)
//     and hB[b,l,h]    = (inputB @ W1[128:])[b,l,h]           (rows 256..8447)
// One virtual row space of 8448 rows x 128 cols. 32 rows per block,
// 256 threads, 4x4 register micro-tile per thread.
// ---------------------------------------------------------------------------
__global__ __launch_bounds__(256) void k1_gemm(
    const float* __restrict__ inA, const float* __restrict__ inB,
    const float* __restrict__ W1, const float* __restrict__ b1,
    float* __restrict__ u, float* __restrict__ hB)
{
    __shared__ float sIn[32 * 128];   // 16 KiB input tile

    const int row0 = blockIdx.x * 32;
    const bool isA = (row0 < BB * KK);     // first 256 virtual rows are A-rows
    const float* src = isA ? (inA + (size_t)row0 * DD)
                           : (inB + (size_t)(row0 - BB * KK) * DD);
    const float* w   = W1 + (isA ? 0 : DD * HH);   // W1[:128] vs W1[128:]
    float* dst       = isA ? (u + (size_t)row0 * HH)
                           : (hB + (size_t)(row0 - BB * KK) * HH);

    const int tid = threadIdx.x;

    // stage 32x128 input tile (coalesced float4 loads)
    #pragma unroll
    for (int j = 0; j < 4; ++j) {
        const int idx = tid + 256 * j;  // float4 index, 1024 total
        reinterpret_cast<float4*>(sIn)[idx] =
            reinterpret_cast<const float4*>(src)[idx];
    }
    __syncthreads();

    const int tx = tid & 31;   // h-group: cols tx*4 .. tx*4+3
    const int ty = tid >> 5;   // row-group: rows ty*4 .. ty*4+3

    float accx[4], accy[4], accz[4], accw[4];
    #pragma unroll
    for (int r = 0; r < 4; ++r) { accx[r] = accy[r] = accz[r] = accw[r] = 0.f; }

    for (int d0 = 0; d0 < DD; d0 += 4) {
        // 4 rows of W1 chunk (global, L2-resident, coalesced across tx)
        float4 w4[4];
        #pragma unroll
        for (int dd = 0; dd < 4; ++dd)
            w4[dd] = ld4(&w[(size_t)(d0 + dd) * HH + tx * 4]);
        // 4 input values per row (LDS b128 over d)
        float a[4][4];
        #pragma unroll
        for (int r = 0; r < 4; ++r) {
            float4 a4 = ld4(&sIn[(ty * 4 + r) * 128 + d0]);
            a[r][0] = a4.x; a[r][1] = a4.y; a[r][2] = a4.z; a[r][3] = a4.w;
        }
        #pragma unroll
        for (int dd = 0; dd < 4; ++dd) {
            const float4 wv = w4[dd];
            #pragma unroll
            for (int r = 0; r < 4; ++r) {
                const float av = a[r][dd];
                accx[r] = fmaf(av, wv.x, accx[r]);
                accy[r] = fmaf(av, wv.y, accy[r]);
                accz[r] = fmaf(av, wv.z, accz[r]);
                accw[r] = fmaf(av, wv.w, accw[r]);
            }
        }
    }

    if (isA) {
        const float4 bb = ld4(&b1[tx * 4]);
        #pragma unroll
        for (int r = 0; r < 4; ++r) {
            accx[r] += bb.x; accy[r] += bb.y; accz[r] += bb.z; accw[r] += bb.w;
        }
    }

    #pragma unroll
    for (int r = 0; r < 4; ++r) {
        float4 o; o.x = accx[r]; o.y = accy[r]; o.z = accz[r]; o.w = accw[r];
        *reinterpret_cast<float4*>(&dst[(size_t)(ty * 4 + r) * HH + tx * 4]) = o;
    }
}

// ---------------------------------------------------------------------------
// k2: scores[b,k,l] = sum_h w2[h] * relu(u[b,k,h] + hB[b,l,h])
// blockIdx.x = kt + 16*lt + 256*b ; thread owns l = lt*256 + tid.
// 8 k-rows per block; u and w2 reads are wave-uniform (scalarize to s_load).
// Writes scores directly into d_out.
// ---------------------------------------------------------------------------
__global__ __launch_bounds__(256) void k2_score(
    const float* __restrict__ u, const float* __restrict__ hB,
    const float* __restrict__ w2, float* __restrict__ out)
{
    int bi = blockIdx.x;
    const int kt = bi & 15;  bi >>= 4;
    const int lt = bi & 15;  bi >>= 4;
    const int b  = bi;

    const int l = lt * 256 + threadIdx.x;
    const float* vrow = hB + ((size_t)b * LL + l) * HH;
    const float* ub   = u + ((size_t)b * KK + kt * 8) * HH;

    float acc[8];
    #pragma unroll
    for (int kk = 0; kk < 8; ++kk) acc[kk] = 0.f;

    for (int h0 = 0; h0 < HH; h0 += 4) {
        const float4 v4 = ld4(&vrow[h0]);
        const float w0 = w2[h0 + 0], w1 = w2[h0 + 1],
                    w2s = w2[h0 + 2], w3 = w2[h0 + 3];
        #pragma unroll
        for (int kk = 0; kk < 8; ++kk) {
            const float* uk = ub + kk * HH + h0;
            const float u0 = uk[0], u1 = uk[1], u2 = uk[2], u3 = uk[3];
            float t;
            t = fmaxf(u0 + v4.x, 0.f); acc[kk] = fmaf(t, w0,  acc[kk]);
            t = fmaxf(u1 + v4.y, 0.f); acc[kk] = fmaf(t, w1,  acc[kk]);
            t = fmaxf(u2 + v4.z, 0.f); acc[kk] = fmaf(t, w2s, acc[kk]);
            t = fmaxf(u3 + v4.w, 0.f); acc[kk] = fmaf(t, w3,  acc[kk]);
        }
    }

    #pragma unroll
    for (int kk = 0; kk < 8; ++kk)
        out[((size_t)b * KK + kt * 8 + kk) * LL + l] = acc[kk];
}

// ---------------------------------------------------------------------------
// k3: in-place row softmax over d_out. One block per (b,k) row of 4096.
// ---------------------------------------------------------------------------
__global__ __launch_bounds__(256) void k3_softmax(float* __restrict__ out)
{
    __shared__ float redm[4];
    __shared__ float reds[4];

    const int row = blockIdx.x;
    float* p = out + (size_t)row * LL;
    const int tid = threadIdx.x;

    float4 x[4];
    #pragma unroll
    for (int j = 0; j < 4; ++j)
        x[j] = reinterpret_cast<const float4*>(p)[tid + 256 * j];

    float m = x[0].x;
    #pragma unroll
    for (int j = 0; j < 4; ++j)
        m = fmaxf(m, fmaxf(fmaxf(x[j].x, x[j].y), fmaxf(x[j].z, x[j].w)));
    #pragma unroll
    for (int off = 32; off > 0; off >>= 1)
        m = fmaxf(m, __shfl_xor(m, off, 64));

    const int lane = tid & 63, wv = tid >> 6;
    if (lane == 0) redm[wv] = m;
    __syncthreads();
    m = fmaxf(fmaxf(redm[0], redm[1]), fmaxf(redm[2], redm[3]));

    float s = 0.f;
    #pragma unroll
    for (int j = 0; j < 4; ++j) {
        x[j].x = expf(x[j].x - m); s += x[j].x;
        x[j].y = expf(x[j].y - m); s += x[j].y;
        x[j].z = expf(x[j].z - m); s += x[j].z;
        x[j].w = expf(x[j].w - m); s += x[j].w;
    }
    #pragma unroll
    for (int off = 32; off > 0; off >>= 1)
        s += __shfl_xor(s, off, 64);
    if (lane == 0) reds[wv] = s;
    __syncthreads();
    s = (reds[0] + reds[1]) + (reds[2] + reds[3]);

    const float inv = 1.0f / s;
    #pragma unroll
    for (int j = 0; j < 4; ++j) {
        x[j].x *= inv; x[j].y *= inv; x[j].z *= inv; x[j].w *= inv;
        reinterpret_cast<float4*>(p)[tid + 256 * j] = x[j];
    }
}

// ---------------------------------------------------------------------------
extern "C" void kernel_launch(void* const* d_in, const int* in_sizes, int n_in,
                              void* d_out, int out_size, void* d_ws, size_t ws_size,
                              hipStream_t stream)
{
    const float* inA = (const float*)d_in[0];
    const float* inB = (const float*)d_in[1];
    const float* W1  = (const float*)d_in[2];
    const float* b1  = (const float*)d_in[3];
    const float* w2  = (const float*)d_in[4];
    float* out = (float*)d_out;

    float* wsf = (float*)d_ws;
    float* u   = wsf;                    // 256*128 floats  = 128 KiB
    float* hB  = wsf + BB * KK * HH;     // 8192*128 floats = 4 MiB

    // k1: 8448 virtual rows / 32 = 264 blocks
    hipLaunchKernelGGL(k1_gemm, dim3(264), dim3(256), 0, stream,
                       inA, inB, W1, b1, u, hB);
    // k2: 16 kt * 16 lt * 2 b = 512 blocks
    hipLaunchKernelGGL(k2_score, dim3(512), dim3(256), 0, stream,
                       u, hB, w2, out);
    // k3: one block per (b,k) row
    hipLaunchKernelGGL(k3_softmax, dim3(BB * KK), dim3(256), 0, stream, out);
}

// Round 3
// 32.726 us; speedup vs baseline: 1.2534x; 1.2534x over previous
//
#include <hip/hip_runtime.h>
#include <hip/hip_fp16.h>
#include <math.h>

// Problem constants (fixed by setup_inputs): B=2, K=128, L=4096, DK=DL=128, HID=128
constexpr int BB = 2;
constexpr int KK = 128;
constexpr int LL = 4096;
constexpr int DD = 128;   // DK == DL
constexpr int HH = 128;   // HID

__device__ __forceinline__ float4 ld4(const float* p) {
    return *reinterpret_cast<const float4*>(p);
}

// packed fp16 max (ROCm headers lack __hmax2) — emits v_pk_max_f16
__device__ __forceinline__ __half2 hmax2(__half2 a, __half2 b) {
    unsigned ua = __builtin_bit_cast(unsigned, a);
    unsigned ub = __builtin_bit_cast(unsigned, b);
    unsigned ud;
    asm("v_pk_max_f16 %0, %1, %2" : "=v"(ud) : "v"(ua), "v"(ub));
    return __builtin_bit_cast(__half2, ud);
}

// ---------------------------------------------------------------------------
// k1: u[b,k,h] = (inputA @ W1[:128])[b,k,h] + b1[h]   -> fp16 (rows 0..255)
//     hB[b,l,h] = (inputB @ W1[128:])[b,l,h]          -> fp16 (rows 256..8447)
// fp32 math, fp16 store. 32 rows/block, 256 threads, 4x4 micro-tile.
// ---------------------------------------------------------------------------
__global__ __launch_bounds__(256) void k1_gemm(
    const float* __restrict__ inA, const float* __restrict__ inB,
    const float* __restrict__ W1, const float* __restrict__ b1,
    __half* __restrict__ uh, __half* __restrict__ vh)
{
    __shared__ __align__(16) float sIn[32 * 128];   // 16 KiB input tile

    const int row0 = blockIdx.x * 32;
    const bool isA = (row0 < BB * KK);
    const float* src = isA ? (inA + (size_t)row0 * DD)
                           : (inB + (size_t)(row0 - BB * KK) * DD);
    const float* w   = W1 + (isA ? 0 : DD * HH);
    __half* dst      = isA ? (uh + (size_t)row0 * HH)
                           : (vh + (size_t)(row0 - BB * KK) * HH);

    const int tid = threadIdx.x;

    #pragma unroll
    for (int j = 0; j < 4; ++j) {
        const int idx = tid + 256 * j;
        reinterpret_cast<float4*>(sIn)[idx] =
            reinterpret_cast<const float4*>(src)[idx];
    }
    __syncthreads();

    const int tx = tid & 31;   // cols tx*4 .. tx*4+3
    const int ty = tid >> 5;   // rows ty*4 .. ty*4+3

    float accx[4], accy[4], accz[4], accw[4];
    #pragma unroll
    for (int r = 0; r < 4; ++r) { accx[r] = accy[r] = accz[r] = accw[r] = 0.f; }

    for (int d0 = 0; d0 < DD; d0 += 4) {
        float4 w4[4];
        #pragma unroll
        for (int dd = 0; dd < 4; ++dd)
            w4[dd] = ld4(&w[(size_t)(d0 + dd) * HH + tx * 4]);
        float a[4][4];
        #pragma unroll
        for (int r = 0; r < 4; ++r) {
            float4 a4 = ld4(&sIn[(ty * 4 + r) * 128 + d0]);
            a[r][0] = a4.x; a[r][1] = a4.y; a[r][2] = a4.z; a[r][3] = a4.w;
        }
        #pragma unroll
        for (int dd = 0; dd < 4; ++dd) {
            const float4 wv = w4[dd];
            #pragma unroll
            for (int r = 0; r < 4; ++r) {
                const float av = a[r][dd];
                accx[r] = fmaf(av, wv.x, accx[r]);
                accy[r] = fmaf(av, wv.y, accy[r]);
                accz[r] = fmaf(av, wv.z, accz[r]);
                accw[r] = fmaf(av, wv.w, accw[r]);
            }
        }
    }

    if (isA) {
        const float4 bb = ld4(&b1[tx * 4]);
        #pragma unroll
        for (int r = 0; r < 4; ++r) {
            accx[r] += bb.x; accy[r] += bb.y; accz[r] += bb.z; accw[r] += bb.w;
        }
    }

    #pragma unroll
    for (int r = 0; r < 4; ++r) {
        __half2 p0 = __floats2half2_rn(accx[r], accy[r]);
        __half2 p1 = __floats2half2_rn(accz[r], accw[r]);
        __half2* dp = reinterpret_cast<__half2*>(dst + (size_t)(ty * 4 + r) * HH + tx * 4);
        dp[0] = p0; dp[1] = p1;
    }
}

// ---------------------------------------------------------------------------
// k2: scores[b,k,l] = sum_h w2[h] * relu(u[b,k,h] + hB[b,l,h])  (fp16 packed)
// grid = b(2) x kt(32, 4 k-rows each) x lt(8, 512 l each); 256 threads,
// 2 l per thread. u-block + w2 staged in LDS (broadcast ds_read_b128).
// fp16 acc flushed to f32 every 16 h. Writes f32 scores to d_out.
// ---------------------------------------------------------------------------
__global__ __launch_bounds__(256) void k2_score(
    const __half* __restrict__ uh, const __half* __restrict__ vh,
    const float* __restrict__ w2, float* __restrict__ out)
{
    __shared__ __align__(16) __half sU[4 * 128];  // 1 KiB
    __shared__ __align__(16) __half sW[128];      // 256 B

    int bi = blockIdx.x;
    const int kt = bi & 31;  bi >>= 5;
    const int lt = bi & 7;   bi >>= 3;
    const int b  = bi;
    const int tid = threadIdx.x;

    if (tid < 64) {
        reinterpret_cast<float4*>(sU)[tid] =
            reinterpret_cast<const float4*>(uh + ((size_t)b * KK + kt * 4) * HH)[tid];
    } else if (tid < 96) {
        const int i = tid - 64;
        float4 wf = ld4(&w2[i * 4]);
        __half2* wp = reinterpret_cast<__half2*>(sW);
        wp[i * 2]     = __floats2half2_rn(wf.x, wf.y);
        wp[i * 2 + 1] = __floats2half2_rn(wf.z, wf.w);
    }
    __syncthreads();

    const int l0 = lt * 512 + tid;          // second l is l0 + 256
    const __half* v0p = vh + ((size_t)b * LL + l0) * HH;
    const __half* v1p = v0p + 256 * HH;

    float facc[4][2];
    #pragma unroll
    for (int k = 0; k < 4; ++k) { facc[k][0] = 0.f; facc[k][1] = 0.f; }

    const __half2 hz = __float2half2_rn(0.f);

    // 16 chunks of 8 h; flush fp16 acc to f32 every 2 chunks (16 h)
    for (int fc = 0; fc < 8; ++fc) {
        __half2 acc[4][2];
        #pragma unroll
        for (int k = 0; k < 4; ++k) { acc[k][0] = hz; acc[k][1] = hz; }

        #pragma unroll
        for (int c = 0; c < 2; ++c) {
            const int hc = fc * 2 + c;   // chunk of 8 halfs
            float4 v0 = ld4(reinterpret_cast<const float*>(v0p + hc * 8));
            float4 v1 = ld4(reinterpret_cast<const float*>(v1p + hc * 8));
            float4 wc = ld4(reinterpret_cast<const float*>(sW + hc * 8));
            const __half2* w2h = reinterpret_cast<const __half2*>(&wc);
            const __half2* v0h = reinterpret_cast<const __half2*>(&v0);
            const __half2* v1h = reinterpret_cast<const __half2*>(&v1);
            #pragma unroll
            for (int k = 0; k < 4; ++k) {
                float4 uc = ld4(reinterpret_cast<const float*>(sU + k * 128 + hc * 8));
                const __half2* uh2 = reinterpret_cast<const __half2*>(&uc);
                #pragma unroll
                for (int j = 0; j < 4; ++j) {
                    __half2 s0 = __hadd2(uh2[j], v0h[j]);
                    __half2 s1 = __hadd2(uh2[j], v1h[j]);
                    acc[k][0] = __hfma2(hmax2(s0, hz), w2h[j], acc[k][0]);
                    acc[k][1] = __hfma2(hmax2(s1, hz), w2h[j], acc[k][1]);
                }
            }
        }
        #pragma unroll
        for (int k = 0; k < 4; ++k) {
            float2 f0 = __half22float2(acc[k][0]);
            float2 f1 = __half22float2(acc[k][1]);
            facc[k][0] += f0.x + f0.y;
            facc[k][1] += f1.x + f1.y;
        }
    }

    #pragma unroll
    for (int k = 0; k < 4; ++k) {
        out[((size_t)b * KK + kt * 4 + k) * LL + l0]       = facc[k][0];
        out[((size_t)b * KK + kt * 4 + k) * LL + l0 + 256] = facc[k][1];
    }
}

// ---------------------------------------------------------------------------
// k3: in-place row softmax over d_out. One block per (b,k) row of 4096.
// ---------------------------------------------------------------------------
__global__ __launch_bounds__(256) void k3_softmax(float* __restrict__ out)
{
    __shared__ float redm[4];
    __shared__ float reds[4];

    const int row = blockIdx.x;
    float* p = out + (size_t)row * LL;
    const int tid = threadIdx.x;

    float4 x[4];
    #pragma unroll
    for (int j = 0; j < 4; ++j)
        x[j] = reinterpret_cast<const float4*>(p)[tid + 256 * j];

    float m = x[0].x;
    #pragma unroll
    for (int j = 0; j < 4; ++j)
        m = fmaxf(m, fmaxf(fmaxf(x[j].x, x[j].y), fmaxf(x[j].z, x[j].w)));
    #pragma unroll
    for (int off = 32; off > 0; off >>= 1)
        m = fmaxf(m, __shfl_xor(m, off, 64));

    const int lane = tid & 63, wv = tid >> 6;
    if (lane == 0) redm[wv] = m;
    __syncthreads();
    m = fmaxf(fmaxf(redm[0], redm[1]), fmaxf(redm[2], redm[3]));

    float s = 0.f;
    #pragma unroll
    for (int j = 0; j < 4; ++j) {
        x[j].x = expf(x[j].x - m); s += x[j].x;
        x[j].y = expf(x[j].y - m); s += x[j].y;
        x[j].z = expf(x[j].z - m); s += x[j].z;
        x[j].w = expf(x[j].w - m); s += x[j].w;
    }
    #pragma unroll
    for (int off = 32; off > 0; off >>= 1)
        s += __shfl_xor(s, off, 64);
    if (lane == 0) reds[wv] = s;
    __syncthreads();
    s = (reds[0] + reds[1]) + (reds[2] + reds[3]);

    const float inv = 1.0f / s;
    #pragma unroll
    for (int j = 0; j < 4; ++j) {
        x[j].x *= inv; x[j].y *= inv; x[j].z *= inv; x[j].w *= inv;
        reinterpret_cast<float4*>(p)[tid + 256 * j] = x[j];
    }
}

// ---------------------------------------------------------------------------
extern "C" void kernel_launch(void* const* d_in, const int* in_sizes, int n_in,
                              void* d_out, int out_size, void* d_ws, size_t ws_size,
                              hipStream_t stream)
{
    const float* inA = (const float*)d_in[0];
    const float* inB = (const float*)d_in[1];
    const float* W1  = (const float*)d_in[2];
    const float* b1  = (const float*)d_in[3];
    const float* w2  = (const float*)d_in[4];
    float* out = (float*)d_out;

    __half* uh = (__half*)d_ws;                          // 256*128 halfs = 64 KiB
    __half* vh = (__half*)((char*)d_ws + 64 * 1024);     // 8192*128 halfs = 2 MiB

    hipLaunchKernelGGL(k1_gemm, dim3(264), dim3(256), 0, stream,
                       inA, inB, W1, b1, uh, vh);
    hipLaunchKernelGGL(k2_score, dim3(512), dim3(256), 0, stream,
                       uh, vh, w2, out);
    hipLaunchKernelGGL(k3_softmax, dim3(BB * KK), dim3(256), 0, stream, out);
}